// Round 9
// baseline (779.159 us; speedup 1.0000x reference)
//
#include <hip/hip_runtime.h>

// Conv2d 3x3 SAME, stride 1: x (16,64,256,256) f32, w (128,64,3,3), bias (128) -> out (16,128,256,256)
//
// V10: fp16 MFMA implicit-GEMM, 3-blocks/CU TLP + 10-slot ring staging.
//  - x -> padded NHWC f16 workspace x_p[n][258][258][64] (1-px zero border).
//  - conv: 1024 blocks (8 strips x 4 bands x 16n x 2 cout-halves) x 256 thr (4 waves x 16 couts).
//    32-col strips; per-iter 4 output rows; 16 iters.
//  - LDS: 10-row ring of 34-col tiles (slot = padded_row % 10). Read slots (P..P+5)%10 and
//    staged slots (P+6..P+9)%10 are provably disjoint -> stage races nothing, no dbuf.
//    43.5 KB tile + 9 KB scratch = 52.7 KB -> 3 blocks/CU = 12 waves/CU (V9: 8, lockstep).
//    Independent blocks cover each other's barrier/epilogue dead time (m114 overlap).
//  - Verified formulas unchanged: source-side swizzle ((s^(c&7))<<4) with linear LDS dest,
//    F = c*128 + (((4h+g)^(c&7))<<4), swapped mfma(bt, af, acc) -> D row=pixel col=cout,
//    scratch stride (36 floats) re-checked conflict-free, NT full-line stores.
//  - Counted vmcnt(8): 5 staging gloads/wave/iter drained, 8 NT stores stay in flight.

typedef _Float16 half8_t __attribute__((ext_vector_type(8)));
typedef float floatx4 __attribute__((ext_vector_type(4)));

#define HH 256
#define WW 256
#define CIN 64
#define COUT 128
#define NB 16

#define XP_RSTRIDE   16512            // halves per padded row (258*64)
#define XP_NSTRIDE   4260096          // halves per n (258*16512)
#define XP_RSTRIDE_B 33024            // bytes per padded row
#define ROW_LDS      4352             // bytes per LDS tile row (34 cols * 128 B)
#define NSLOT        10

__device__ inline void gload_lds16(const void* g, void* l) {
    __builtin_amdgcn_global_load_lds(
        (const __attribute__((address_space(1))) unsigned int*)g,
        (__attribute__((address_space(3))) unsigned int*)l, 16, 0, 0);
}

// ---------- pass 1a: weights OIHW f32 -> w_t[9][8][128][8] f16 ----------
__global__ void Conv2d_wprep_kernel(const float* __restrict__ w, _Float16* __restrict__ w_t) {
    int idx = blockIdx.x * 256 + threadIdx.x;
    if (idx >= 9 * 8 * 128 * 8) return;
    const int j = idx & 7, cout = (idx >> 3) & 127, s = (idx >> 10) & 7, t = idx >> 13;
    w_t[idx] = (_Float16)w[(cout * 64 + s * 8 + j) * 9 + t];
}

// ---------- pass 1b-zero: zero the 1-px border of x_p ----------
__global__ void Conv2d_xpad_zero_kernel(_Float16* __restrict__ xp) {
    const int idx = blockIdx.x * 256 + threadIdx.x;   // 16B units, 8224 per n
    const int n = blockIdx.y;
    if (idx >= 8224) return;
    size_t off;  // in halves
    if (idx < 2064)      off = (size_t)idx * 8;                                    // row 0
    else if (idx < 4128) off = (size_t)257 * XP_RSTRIDE + (size_t)(idx - 2064) * 8; // row 257
    else if (idx < 6176) { const int t = idx - 4128;                               // col 0
        off = (size_t)(1 + (t >> 3)) * XP_RSTRIDE + (size_t)(t & 7) * 8; }
    else { const int t = idx - 6176;                                               // col 257
        off = (size_t)(1 + (t >> 3)) * XP_RSTRIDE + 257 * 64 + (size_t)(t & 7) * 8; }
    int4 z = {0, 0, 0, 0};
    *(int4*)(xp + (size_t)n * XP_NSTRIDE + off) = z;
}

// ---------- pass 1b: x NCHW f32 -> padded NHWC f16 (LDS-free transpose) ----------
__global__ __launch_bounds__(256) void Conv2d_xprep_kernel(const float* __restrict__ x,
                                                           _Float16* __restrict__ xp) {
    const int tid = threadIdx.x;
    const int u = tid & 7, colq = tid >> 3;
    const int n = blockIdx.z, h = blockIdx.y;
    const int col0 = blockIdx.x * 128 + colq * 4;

    float4 in[8];
#pragma unroll
    for (int j = 0; j < 8; ++j)
        in[j] = *(const float4*)(x + ((size_t)((n * 64 + u * 8 + j) * 256 + h) * 256) + col0);

    _Float16* dst = xp + (size_t)n * XP_NSTRIDE + (size_t)(h + 1) * XP_RSTRIDE +
                    (size_t)(col0 + 1) * 64 + u * 8;
#pragma unroll
    for (int i = 0; i < 4; ++i) {
        half8_t hv;
#pragma unroll
        for (int j = 0; j < 8; ++j) hv[j] = (_Float16)((const float*)&in[j])[i];
        *(half8_t*)(dst + (size_t)i * 64) = hv;
    }
}

// ---------- conv: ring-staged strips, register weights, 3 blocks/CU ----------
__global__ __launch_bounds__(256, 3) void Conv2dManual_77695958385099_kernel(
    const _Float16* __restrict__ xp, const _Float16* __restrict__ w_t,
    const float* __restrict__ bias, float* __restrict__ out) {
    __shared__ __align__(16) unsigned char xs[NSLOT * ROW_LDS];  // 43520 B
    __shared__ __align__(16) float esc[4][576];                  // 9216 B (16 cout x 36)
    const int tid = threadIdx.x;
    const int l = tid & 63, wvid = tid >> 6;   // wave -> couts co0 + wvid*16 .. +15
    const int g = l >> 4, ln = l & 15;
    const int strip = blockIdx.x;              // 32-col strip
    const int band = blockIdx.y;               // rows band*64..+63
    const int ch = blockIdx.z & 1, n = blockIdx.z >> 1;
    const int ow0 = strip * 32;
    const int co0 = ch * 64;

    // ---- persistent weights: A[h][tap], 18 x half8 = 72 VGPR; lane ln -> cout ----
    const char* wl = (const char*)w_t + g * 2048 + (co0 + wvid * 16 + ln) * 16;
    half8_t A[2][9];
#pragma unroll
    for (int h = 0; h < 2; ++h)
#pragma unroll
        for (int tp = 0; tp < 9; ++tp)
            A[h][tp] = *(const half8_t*)(wl + h * 8192 + tp * 16384);

    const float bv = bias[co0 + wvid * 16 + ln];

    // ---- per-lane LDS byte offsets within a row-slot: F[cgf][kx][h] ----
    int F[2][3][2];
#pragma unroll
    for (int cgf = 0; cgf < 2; ++cgf)
#pragma unroll
        for (int kx = 0; kx < 3; ++kx)
#pragma unroll
            for (int h = 0; h < 2; ++h) {
                const int c = cgf * 16 + kx + ln;
                F[cgf][kx][h] = c * 128 + (((4 * h + g) ^ (c & 7)) << 4);
            }

    const char* xbase = (const char*)xp + (size_t)n * XP_NSTRIDE * 2 + (size_t)ow0 * 128;
    const int P0 = band * 64;   // first padded row needed (== first output row index)

    // ---- initial stage: padded rows P0..P0+5 into slots pr%10 ----
#pragma unroll 1
    for (int j = 0; j < 6; ++j) {
        const int pr = P0 + j;
        const int slot = pr % NSLOT;
        const char* gr = xbase + (size_t)pr * XP_RSTRIDE_B;
        {   // full pass: 256 units (cols 0..31)
            const int c = tid >> 3, s = tid & 7;
            gload_lds16(gr + c * 128 + ((s ^ (c & 7)) << 4),
                        xs + slot * ROW_LDS + ((tid & ~63) << 4));
        }
        if ((tid >> 6) == (j & 3) && (tid & 63) < 16) {  // tail: units 256..271 (cols 32,33)
            const int k = tid & 15;
            const int c = 32 + (k >> 3), s = k & 7;
            gload_lds16(gr + c * 128 + ((s ^ (c & 7)) << 4),
                        xs + slot * ROW_LDS + 4096);
        }
    }
    asm volatile("s_waitcnt vmcnt(0) lgkmcnt(0)" ::: "memory");
    __builtin_amdgcn_s_barrier();
    __builtin_amdgcn_sched_barrier(0);

    int s0 = P0 % NSLOT;   // slot of first needed row this iter
#pragma unroll 1
    for (int it = 0; it < 16; ++it) {
        // ---- stage 4 rows for it+1 (slots provably disjoint from this iter's reads) ----
        if (it < 15) {
            const int prn0 = P0 + it * 4 + 6;
#pragma unroll
            for (int j = 0; j < 4; ++j) {
                const int pr = prn0 + j;
                const int slot = pr % NSLOT;
                const char* gr = xbase + (size_t)pr * XP_RSTRIDE_B;
                {
                    const int c = tid >> 3, s = tid & 7;
                    gload_lds16(gr + c * 128 + ((s ^ (c & 7)) << 4),
                                xs + slot * ROW_LDS + ((tid & ~63) << 4));
                }
                if ((tid >> 6) == j && (tid & 63) < 16) {
                    const int k = tid & 15;
                    const int c = 32 + (k >> 3), s = k & 7;
                    gload_lds16(gr + c * 128 + ((s ^ (c & 7)) << 4),
                                xs + slot * ROW_LDS + 4096);
                }
            }
        }

        // ---- per-iter row-slot byte offsets ----
        int roff[6];
#pragma unroll
        for (int t = 0; t < 6; ++t) {
            int st = s0 + t;
            if (st >= NSLOT) st -= NSLOT;
            roff[t] = st * ROW_LDS;
        }

        floatx4 acc[4][2];   // [rr][cgf]; components = 4 consecutive pixels
#pragma unroll
        for (int rr = 0; rr < 4; ++rr)
#pragma unroll
            for (int cgf = 0; cgf < 2; ++cgf) acc[rr][cgf] = (floatx4){bv, bv, bv, bv};

#pragma unroll
        for (int kx = 0; kx < 3; ++kx)
#pragma unroll
            for (int h = 0; h < 2; ++h)
#pragma unroll
                for (int cgf = 0; cgf < 2; ++cgf) {
                    const unsigned char* bp = xs + F[cgf][kx][h];
                    half8_t bt[6];
#pragma unroll
                    for (int t = 0; t < 6; ++t)
                        bt[t] = *(const half8_t*)(bp + roff[t]);
#pragma unroll
                    for (int ky = 0; ky < 3; ++ky) {
                        const half8_t af = A[h][ky * 3 + kx];
#pragma unroll
                        for (int rr = 0; rr < 4; ++rr)
                            acc[rr][cgf] = __builtin_amdgcn_mfma_f32_16x16x32_f16(
                                bt[rr + ky], af, acc[rr][cgf], 0, 0, 0);  // D row=pixel
                    }
                }

        // ---- epilogue: b128 scratch transpose -> full-line NT dwordx4 stores ----
        float* scr = &esc[wvid][0];
        float* obase = out + ((size_t)(n * 128 + co0 + wvid * 16)) * 65536 +
                       (size_t)(P0 + it * 4) * 256 + ow0;
#pragma unroll
        for (int rr = 0; rr < 4; ++rr) {
#pragma unroll
            for (int cgf = 0; cgf < 2; ++cgf)
                *(floatx4*)(scr + ln * 36 + cgf * 16 + g * 4) = acc[rr][cgf];
#pragma unroll
            for (int q = 0; q < 2; ++q) {
                const int co = q * 8 + g * 2 + (ln >> 3);
                const floatx4 v = *(const floatx4*)(scr + co * 36 + (ln & 7) * 4);
                __builtin_nontemporal_store(
                    v, (floatx4*)(obase + (size_t)co * 65536 + rr * 256 + (ln & 7) * 4));
            }
        }

        if (it < 15) {
            // Drain 5 staging gloads (oldest); leave this iter's 8 NT stores in flight.
            asm volatile("s_waitcnt vmcnt(8) lgkmcnt(0)" ::: "memory");
            __builtin_amdgcn_s_barrier();
            __builtin_amdgcn_sched_barrier(0);
        }
        s0 += 4;
        if (s0 >= NSLOT) s0 -= NSLOT;
    }
}

// ---------- fallback (proven V2 fp32) if workspace too small ----------
__global__ __launch_bounds__(256) void Conv2d_fallback_kernel(
    const float* __restrict__ x, const float* __restrict__ w,
    const float* __restrict__ bias, float* __restrict__ out) {
    const int tx = threadIdx.x & 15, ty = threadIdx.x >> 4;
    const int ow0 = blockIdx.x * 64 + tx * 4;
    const int oh = blockIdx.y * 16 + ty;
    const int gg = blockIdx.z & 7, n = blockIdx.z >> 3;
    const int co = gg * 16;
    float acc[16][4];
#pragma unroll
    for (int c = 0; c < 16; ++c) {
        const float b = bias[co + c];
#pragma unroll
        for (int p = 0; p < 4; ++p) acc[c][p] = b;
    }
    const float* xn = x + (size_t)n * CIN * HH * WW;
    const float* wb = w + (size_t)co * CIN * 9;
    for (int ci = 0; ci < CIN; ++ci) {
        const float* xc = xn + (size_t)ci * HH * WW;
        float in[3][6];
#pragma unroll
        for (int ky = 0; ky < 3; ++ky) {
            const int iy = oh + ky - 1;
            if ((unsigned)iy < (unsigned)HH) {
                const float* row = xc + iy * WW;
                const float4 v = *(const float4*)(row + ow0);
                in[ky][1] = v.x; in[ky][2] = v.y; in[ky][3] = v.z; in[ky][4] = v.w;
                in[ky][0] = (ow0 > 0) ? row[ow0 - 1] : 0.0f;
                in[ky][5] = (ow0 < WW - 4) ? row[ow0 + 4] : 0.0f;
            } else {
#pragma unroll
                for (int j = 0; j < 6; ++j) in[ky][j] = 0.0f;
            }
        }
        const float* wc2 = wb + ci * 9;
#pragma unroll
        for (int c = 0; c < 16; ++c) {
            const float* wcc = wc2 + (size_t)c * CIN * 9;
#pragma unroll
            for (int ky = 0; ky < 3; ++ky)
#pragma unroll
                for (int kx = 0; kx < 3; ++kx) {
                    const float wv2 = wcc[ky * 3 + kx];
#pragma unroll
                    for (int p = 0; p < 4; ++p) acc[c][p] += in[ky][kx + p] * wv2;
                }
        }
    }
    const size_t hw = (size_t)HH * WW;
    float* ob = out + ((size_t)n * COUT + co) * hw + (size_t)oh * WW + ow0;
#pragma unroll
    for (int c = 0; c < 16; ++c) {
        float4 v;
        v.x = acc[c][0]; v.y = acc[c][1]; v.z = acc[c][2]; v.w = acc[c][3];
        *(float4*)(ob + (size_t)c * hw) = v;
    }
}

extern "C" void kernel_launch(void* const* d_in, const int* in_sizes, int n_in,
                              void* d_out, int out_size, void* d_ws, size_t ws_size,
                              hipStream_t stream) {
    const float* x = (const float*)d_in[0];
    const float* w = (const float*)d_in[1];
    const float* b = (const float*)d_in[2];
    float* out = (float*)d_out;

    const size_t xp_bytes = (size_t)NB * XP_NSTRIDE * 2;      // 136.3 MB
    const size_t wt_bytes = (size_t)9 * 8 * 128 * 8 * 2;      // 144 KiB

    if (ws_size >= xp_bytes + wt_bytes) {
        char* ws = (char*)d_ws;
        _Float16* xp = (_Float16*)ws;
        _Float16* w_t = (_Float16*)(ws + xp_bytes);
        Conv2d_wprep_kernel<<<dim3(288), 256, 0, stream>>>(w, w_t);
        Conv2d_xpad_zero_kernel<<<dim3(33, 16), 256, 0, stream>>>(xp);
        Conv2d_xprep_kernel<<<dim3(2, 256, 16), 256, 0, stream>>>(x, xp);
        Conv2dManual_77695958385099_kernel<<<dim3(8, 4, 32), 256, 0, stream>>>(
            xp, w_t, b, out);
    } else {
        dim3 grid(WW / 64, HH / 16, NB * (COUT / 16));
        Conv2d_fallback_kernel<<<grid, 256, 0, stream>>>(x, w, b, out);
    }
}

// Round 10
// 749.831 us; speedup vs baseline: 1.0391x; 1.0391x over previous
//
#include <hip/hip_runtime.h>

// Conv2d 3x3 SAME, stride 1: x (16,64,256,256) f32, w (128,64,3,3), bias (128) -> out (16,128,256,256)
//
// V11: FUSED fp16 MFMA implicit-GEMM — xprep/xpad folded into conv (T14 reg-staging).
//  - No x_p workspace: conv reads x (f32 NCHW) directly, converts to f16, ds_writes
//    swizzled NHWC tiles. Removes 2 dispatches + ~250 MB HBM traffic vs V9.
//  - Geometry = V9 (best: 763us): 256 blocks (4 strips x 4 bands x 16 n) x 512 thr,
//    8 waves x 16 couts, per-wave A = 18 half8 = 72 VGPR register-persistent.
//  - LDS: 10-slot row ring (66 cols x 128 B), slot = padded_row % 10; read slots
//    (b..b+5) and staged slots (b+6..b+9) provably disjoint (V10-verified) -> the
//    late ds_writes race nothing; one barrier per iter. 84.5 KB + 34.8 KB esc.
//  - Staging per iter: issue 8 float4 loads (+16 scalar edge loads, 8 lanes/row-grp)
//    EARLY, hold in regs across MFMA (T14), cvt+ds_write LATE after the epilogue.
//    Write swizzle (su^(c&7))<<4 matches the read-side F formula (both-sides rule).
//    Boundary rows/cols zero-filled in regs (replaces x_p's zero border).
//  - MFMA core + epilogue bit-identical to V9 (verified): swapped mfma(bt, af, acc)
//    D row=pixel col=cout; b128 scratch transpose; NT full-128B-line dwordx4 stores.
//  - Compiler-managed vmcnt for staging loads (auto counted past the NT stores);
//    raw s_barrier + lgkmcnt(0) only (no vmcnt(0) drain of stores).

typedef _Float16 half8_t __attribute__((ext_vector_type(8)));
typedef float floatx4 __attribute__((ext_vector_type(4)));

#define HH 256
#define WW 256
#define CIN 64
#define COUT 128
#define NB 16

#define ROW_LDS 8448              // bytes per LDS tile row (66 cols * 128 B)
#define NSLOT   10

// ---------- pass 1a: weights OIHW f32 -> w_t[9][8][128][8] f16 ----------
__global__ void Conv2d_wprep_kernel(const float* __restrict__ w, _Float16* __restrict__ w_t) {
    int idx = blockIdx.x * 256 + threadIdx.x;
    if (idx >= 9 * 8 * 128 * 8) return;
    const int j = idx & 7, cout = (idx >> 3) & 127, s = (idx >> 10) & 7, t = idx >> 13;
    w_t[idx] = (_Float16)w[(cout * 64 + s * 8 + j) * 9 + t];
}

// ---------- fused conv ----------
__global__ __launch_bounds__(512, 2) void Conv2dManual_77695958385099_kernel(
    const float* __restrict__ x, const _Float16* __restrict__ w_t,
    const float* __restrict__ bias, float* __restrict__ out) {
    __shared__ __align__(16) unsigned char xs[NSLOT * ROW_LDS];  // 84480 B
    __shared__ __align__(16) float esc[8][1088];                 // 34816 B
    const int tid = threadIdx.x;
    const int l = tid & 63, wvid = tid >> 6;    // wave -> couts wvid*16..+15
    const int g = l >> 4, ln = l & 15;
    const int ow0 = blockIdx.x * 64;
    const int band = blockIdx.y;                // output rows band*64..+63
    const int n = blockIdx.z;
    const int P0 = band * 64;                   // first padded row of the band

    // staging roles: 4 row-groups of 128 threads
    const int rw = tid >> 7;                    // row group 0..3
    const int t7 = tid & 127;
    const int su = t7 & 7;                      // ci-unit (8 ci)
    const int cb = t7 >> 3;                     // col block 0..15 (4 cols each)
    const bool isEdge = (t7 >= 120);            // 8 lanes/row-group handle halo cols
    const int eu = t7 - 120;                    // edge ci-unit

    // ---- persistent weights: A[h][tap], 18 x half8 = 72 VGPR; lane ln -> cout ----
    const char* wl = (const char*)w_t + g * 2048 + (wvid * 16 + ln) * 16;
    half8_t A[2][9];
#pragma unroll
    for (int h = 0; h < 2; ++h)
#pragma unroll
        for (int tp = 0; tp < 9; ++tp)
            A[h][tp] = *(const half8_t*)(wl + h * 8192 + tp * 16384);

    const float bv = bias[wvid * 16 + ln];

    // ---- per-lane LDS byte offsets: F[cgf][kx][h] (verified formula) ----
    int F[4][3][2];
#pragma unroll
    for (int cgf = 0; cgf < 4; ++cgf)
#pragma unroll
        for (int kx = 0; kx < 3; ++kx)
#pragma unroll
            for (int h = 0; h < 2; ++h) {
                const int c = cgf * 16 + kx + ln;
                F[cgf][kx][h] = c * 128 + (((4 * h + g) ^ (c & 7)) << 4);
            }

    // ---- staging helpers (both-sides swizzle; zero-fill replaces padded border) ----
    auto stage_load = [&](int pr, float4 (&ld)[8], float (&e0)[8], float (&e1)[8]) {
        const int gr = pr - 1;                   // padded row -> global row
        const bool vrow = ((unsigned)gr < 256u);
        if (vrow) {
            const float4* xr = (const float4*)x +
                               (((size_t)(n * 64 + su * 8)) << 14) +
                               (size_t)gr * 64 + (ow0 >> 2) + cb;
#pragma unroll
            for (int j = 0; j < 8; ++j) ld[j] = xr[(size_t)j << 14];
        } else {
#pragma unroll
            for (int j = 0; j < 8; ++j) ld[j] = (float4){0.f, 0.f, 0.f, 0.f};
        }
        if (isEdge) {
            const float* xe = x + (((size_t)(n * 64 + eu * 8)) << 16) + (size_t)gr * 256;
#pragma unroll
            for (int j = 0; j < 8; ++j) {
                e0[j] = (vrow && ow0 > 0)        ? xe[((size_t)j << 16) + ow0 - 1]  : 0.f;
                e1[j] = (vrow && ow0 + 64 < 256) ? xe[((size_t)j << 16) + ow0 + 64] : 0.f;
            }
        }
    };
    auto stage_write = [&](int pr, const float4 (&ld)[8], const float (&e0)[8],
                           const float (&e1)[8]) {
        const unsigned sb = (unsigned)(pr % NSLOT) * ROW_LDS;
#pragma unroll
        for (int k = 0; k < 4; ++k) {
            const int c = 1 + cb * 4 + k;
            half8_t hv;
#pragma unroll
            for (int j = 0; j < 8; ++j) hv[j] = (_Float16)((const float*)&ld[j])[k];
            *(half8_t*)(xs + sb + c * 128 + ((su ^ (c & 7)) << 4)) = hv;
        }
        if (isEdge) {
            half8_t h0, h1;
#pragma unroll
            for (int j = 0; j < 8; ++j) {
                h0[j] = (_Float16)e0[j];
                h1[j] = (_Float16)e1[j];
            }
            *(half8_t*)(xs + sb + (eu << 4)) = h0;                      // c = 0
            *(half8_t*)(xs + sb + 65 * 128 + ((eu ^ 1) << 4)) = h1;     // c = 65
        }
    };

    // ---- prologue: stage padded rows P0..P0+5 ----
    {
        float4 ld[8]; float e0[8], e1[8];
        stage_load(P0 + rw, ld, e0, e1);
        stage_write(P0 + rw, ld, e0, e1);
        if (rw < 2) {
            stage_load(P0 + 4 + rw, ld, e0, e1);
            stage_write(P0 + 4 + rw, ld, e0, e1);
        }
    }
    asm volatile("s_waitcnt lgkmcnt(0)" ::: "memory");
    __builtin_amdgcn_s_barrier();
    __builtin_amdgcn_sched_barrier(0);

    int s0 = P0 % NSLOT;
#pragma unroll 1
    for (int it = 0; it < 16; ++it) {
        // ---- EARLY: issue next-tile f32 loads, hold in regs across compute ----
        float4 ld[8]; float e0[8], e1[8];
        const int prn = P0 + it * 4 + 6 + rw;
        if (it < 15) stage_load(prn, ld, e0, e1);
        __builtin_amdgcn_sched_barrier(0);   // pin load issue before compute

        // ---- ring slot offsets for this iter's 6 rows ----
        int roff[6];
#pragma unroll
        for (int tt = 0; tt < 6; ++tt) {
            int st = s0 + tt;
            if (st >= NSLOT) st -= NSLOT;
            roff[tt] = st * ROW_LDS;
        }

        floatx4 acc[4][4];   // [rr][cgf]; components = 4 consecutive pixels
#pragma unroll
        for (int rr = 0; rr < 4; ++rr)
#pragma unroll
            for (int cgf = 0; cgf < 4; ++cgf) acc[rr][cgf] = (floatx4){bv, bv, bv, bv};

#pragma unroll
        for (int kx = 0; kx < 3; ++kx)
#pragma unroll
            for (int h = 0; h < 2; ++h)
#pragma unroll
                for (int cgf = 0; cgf < 4; ++cgf) {
                    const unsigned char* bp = xs + F[cgf][kx][h];
                    half8_t bt[6];
#pragma unroll
                    for (int tt = 0; tt < 6; ++tt)
                        bt[tt] = *(const half8_t*)(bp + roff[tt]);
#pragma unroll
                    for (int ky = 0; ky < 3; ++ky) {
                        const half8_t af = A[h][ky * 3 + kx];
#pragma unroll
                        for (int rr = 0; rr < 4; ++rr)
                            acc[rr][cgf] = __builtin_amdgcn_mfma_f32_16x16x32_f16(
                                bt[rr + ky], af, acc[rr][cgf], 0, 0, 0);  // D row=pixel
                    }
                }

        // ---- epilogue: b128 scratch transpose -> full-line NT dwordx4 stores ----
        float* scr = &esc[wvid][0];
        float* obase = out + ((size_t)(n * 128 + wvid * 16)) * 65536 +
                       (size_t)(P0 + it * 4) * 256 + ow0;
#pragma unroll
        for (int rr = 0; rr < 4; ++rr) {
#pragma unroll
            for (int cgf = 0; cgf < 4; ++cgf)
                *(floatx4*)(scr + ln * 68 + cgf * 16 + g * 4) = acc[rr][cgf];
#pragma unroll
            for (int q = 0; q < 4; ++q) {
                const int co = q * 4 + g;
                const floatx4 v = *(const floatx4*)(scr + co * 68 + ln * 4);
                __builtin_nontemporal_store(
                    v, (floatx4*)(obase + (size_t)co * 65536 + rr * 256 + ln * 4));
            }
        }

        // ---- LATE: convert + ds_write next tile; barrier publishes it ----
        if (it < 15) {
            stage_write(prn, ld, e0, e1);     // compiler waits loads, not NT stores
            asm volatile("s_waitcnt lgkmcnt(0)" ::: "memory");
            __builtin_amdgcn_s_barrier();
            __builtin_amdgcn_sched_barrier(0);
        }
        s0 += 4;
        if (s0 >= NSLOT) s0 -= NSLOT;
    }
}

// ---------- fallback (proven V2 fp32) if workspace too small ----------
__global__ __launch_bounds__(256) void Conv2d_fallback_kernel(
    const float* __restrict__ x, const float* __restrict__ w,
    const float* __restrict__ bias, float* __restrict__ out) {
    const int tx = threadIdx.x & 15, ty = threadIdx.x >> 4;
    const int ow0 = blockIdx.x * 64 + tx * 4;
    const int oh = blockIdx.y * 16 + ty;
    const int gg = blockIdx.z & 7, n = blockIdx.z >> 3;
    const int co = gg * 16;
    float acc[16][4];
#pragma unroll
    for (int c = 0; c < 16; ++c) {
        const float b = bias[co + c];
#pragma unroll
        for (int p = 0; p < 4; ++p) acc[c][p] = b;
    }
    const float* xn = x + (size_t)n * CIN * HH * WW;
    const float* wb = w + (size_t)co * CIN * 9;
    for (int ci = 0; ci < CIN; ++ci) {
        const float* xc = xn + (size_t)ci * HH * WW;
        float in[3][6];
#pragma unroll
        for (int ky = 0; ky < 3; ++ky) {
            const int iy = oh + ky - 1;
            if ((unsigned)iy < (unsigned)HH) {
                const float* row = xc + iy * WW;
                const float4 v = *(const float4*)(row + ow0);
                in[ky][1] = v.x; in[ky][2] = v.y; in[ky][3] = v.z; in[ky][4] = v.w;
                in[ky][0] = (ow0 > 0) ? row[ow0 - 1] : 0.0f;
                in[ky][5] = (ow0 < WW - 4) ? row[ow0 + 4] : 0.0f;
            } else {
#pragma unroll
                for (int j = 0; j < 6; ++j) in[ky][j] = 0.0f;
            }
        }
        const float* wc2 = wb + ci * 9;
#pragma unroll
        for (int c = 0; c < 16; ++c) {
            const float* wcc = wc2 + (size_t)c * CIN * 9;
#pragma unroll
            for (int ky = 0; ky < 3; ++ky)
#pragma unroll
                for (int kx = 0; kx < 3; ++kx) {
                    const float wv2 = wcc[ky * 3 + kx];
#pragma unroll
                    for (int p = 0; p < 4; ++p) acc[c][p] += in[ky][kx + p] * wv2;
                }
        }
    }
    const size_t hw = (size_t)HH * WW;
    float* ob = out + ((size_t)n * COUT + co) * hw + (size_t)oh * WW + ow0;
#pragma unroll
    for (int c = 0; c < 16; ++c) {
        float4 v;
        v.x = acc[c][0]; v.y = acc[c][1]; v.z = acc[c][2]; v.w = acc[c][3];
        *(float4*)(ob + (size_t)c * hw) = v;
    }
}

extern "C" void kernel_launch(void* const* d_in, const int* in_sizes, int n_in,
                              void* d_out, int out_size, void* d_ws, size_t ws_size,
                              hipStream_t stream) {
    const float* x = (const float*)d_in[0];
    const float* w = (const float*)d_in[1];
    const float* b = (const float*)d_in[2];
    float* out = (float*)d_out;

    const size_t wt_bytes = (size_t)9 * 8 * 128 * 8 * 2;      // 144 KiB

    if (ws_size >= wt_bytes) {
        _Float16* w_t = (_Float16*)d_ws;
        Conv2d_wprep_kernel<<<dim3(288), 256, 0, stream>>>(w, w_t);
        Conv2dManual_77695958385099_kernel<<<dim3(4, 4, 16), 512, 0, stream>>>(
            x, w_t, b, out);
    } else {
        dim3 grid(WW / 64, HH / 16, NB * (COUT / 16));
        Conv2d_fallback_kernel<<<grid, 256, 0, stream>>>(x, w, b, out);
    }
}